// Round 1
// baseline (1086.766 us; speedup 1.0000x reference)
//
#include <hip/hip_runtime.h>

// ---------------------------------------------------------------------------
// Attention_89361089560777: B=8, S=1024, H=768, nh=12, d=64
//   out = proj_o( softmax( QK^T/8 + bias, masked->~0 ) V )
// Pipeline: prep_weights -> qkv_gemm -> attn_kernel -> out_gemm
// Workspace: WT(4x768x768 bf16) + Q,K,Vt,Ob (each 8x12x1024x64 bf16) = 55 MB
// ---------------------------------------------------------------------------

typedef __attribute__((ext_vector_type(8))) __bf16 bf16x8;
typedef __attribute__((ext_vector_type(4))) float floatx4;
using bf16 = __bf16;

#define HID 768
#define NHEAD 12
#define DHEAD 64
#define SEQ 1024
#define NBATCH 8
#define WELEM (HID * HID)                         // 589824
#define QKVELEM (NBATCH * NHEAD * SEQ * DHEAD)    // 6291456

__device__ __forceinline__ floatx4 mfma_bf16(bf16x8 a, bf16x8 b, floatx4 c) {
  return __builtin_amdgcn_mfma_f32_16x16x32_bf16(a, b, c, 0, 0, 0);
}

// ---------------------------------------------------------------------------
// Weight prep: WT[m][n][k] = bf16(W_m[k][n]); LDS-tiled transpose, both sides
// coalesced.
// ---------------------------------------------------------------------------
__global__ void prep_weights(const float* __restrict__ Wq, const float* __restrict__ Wk,
                             const float* __restrict__ Wv, const float* __restrict__ Wo,
                             bf16* __restrict__ WT) {
  __shared__ float t[32][33];
  const int m = blockIdx.z;
  const float* W = (m == 0) ? Wq : (m == 1) ? Wk : (m == 2) ? Wv : Wo;
  const int k0 = blockIdx.x * 32, n0 = blockIdx.y * 32;
  const int tx = threadIdx.x, ty = threadIdx.y;
#pragma unroll
  for (int i = 0; i < 4; ++i)
    t[ty + 8 * i][tx] = W[(size_t)(k0 + ty + 8 * i) * HID + n0 + tx];
  __syncthreads();
  bf16* o = WT + (size_t)m * WELEM;
#pragma unroll
  for (int i = 0; i < 4; ++i)
    o[(size_t)(n0 + ty + 8 * i) * HID + k0 + tx] = (bf16)t[tx][ty + 8 * i];
}

// ---------------------------------------------------------------------------
// QKV projection GEMM: C = h @ W_mat + b_mat   (M=8192, N=768, K=768)
// 64x64 block tile, 4 waves (2x2), each wave 2x2 of 16x16x32 MFMA, BK=32.
// mat 0 -> Qb[b][h][s][d] * 0.125 ; mat 1 -> Kb[b][h][s][d] ; mat 2 -> Vt[b][h][d][s]
// ---------------------------------------------------------------------------
__launch_bounds__(256)
__global__ void qkv_gemm(const float* __restrict__ X, const bf16* __restrict__ WT,
                         const float* __restrict__ bq, const float* __restrict__ bk,
                         const float* __restrict__ bv,
                         bf16* __restrict__ Qb, bf16* __restrict__ Kb,
                         bf16* __restrict__ Vt) {
  __shared__ __align__(16) bf16 As[64][32];  // [m][k]
  __shared__ __align__(16) bf16 Bs[64][32];  // [n][k]
  const int mat = blockIdx.z;
  const int bn = blockIdx.x * 64;
  const int bm = blockIdx.y * 64;
  const bf16* W = WT + (size_t)mat * WELEM;
  const float* bias = (mat == 0) ? bq : (mat == 1) ? bk : bv;

  const int tid = threadIdx.x;
  const int lane = tid & 63, warp = tid >> 6;
  const int fr = lane & 15, quad = lane >> 4;
  const int wm = (warp >> 1) * 32, wn = (warp & 1) * 32;

  floatx4 acc00 = {0.f, 0.f, 0.f, 0.f}, acc01 = {0.f, 0.f, 0.f, 0.f};
  floatx4 acc10 = {0.f, 0.f, 0.f, 0.f}, acc11 = {0.f, 0.f, 0.f, 0.f};

  const int sr = tid >> 2, scol = (tid & 3) * 8;
  const float* xsrc = X + (size_t)(bm + sr) * HID + scol;
  const bf16* wsrc = W + (size_t)(bn + sr) * HID + scol;

  for (int k0 = 0; k0 < HID; k0 += 32) {
    float4 f0 = *(const float4*)(xsrc + k0);
    float4 f1 = *(const float4*)(xsrc + k0 + 4);
    uint4 wv = *(const uint4*)(wsrc + k0);
    bf16x8 av;
    av[0] = (bf16)f0.x; av[1] = (bf16)f0.y; av[2] = (bf16)f0.z; av[3] = (bf16)f0.w;
    av[4] = (bf16)f1.x; av[5] = (bf16)f1.y; av[6] = (bf16)f1.z; av[7] = (bf16)f1.w;
    *(bf16x8*)&As[sr][scol] = av;
    *(uint4*)&Bs[sr][scol] = wv;
    __syncthreads();
    bf16x8 a0 = *(const bf16x8*)&As[wm + fr][quad * 8];
    bf16x8 a1 = *(const bf16x8*)&As[wm + 16 + fr][quad * 8];
    bf16x8 b0 = *(const bf16x8*)&Bs[wn + fr][quad * 8];
    bf16x8 b1 = *(const bf16x8*)&Bs[wn + 16 + fr][quad * 8];
    acc00 = mfma_bf16(a0, b0, acc00);
    acc01 = mfma_bf16(a0, b1, acc01);
    acc10 = mfma_bf16(a1, b0, acc10);
    acc11 = mfma_bf16(a1, b1, acc11);
    __syncthreads();
  }

#pragma unroll
  for (int mi = 0; mi < 2; ++mi) {
#pragma unroll
    for (int ni = 0; ni < 2; ++ni) {
      floatx4 acc = (mi == 0) ? ((ni == 0) ? acc00 : acc01)
                              : ((ni == 0) ? acc10 : acc11);
#pragma unroll
      for (int r = 0; r < 4; ++r) {
        const int grow = bm + wm + mi * 16 + quad * 4 + r;  // global row (b*S+s)
        const int gcol = bn + wn + ni * 16 + fr;            // global col (head*64+dc)
        float v = acc[r] + bias[gcol];
        const int bb = grow >> 10, ss = grow & 1023;
        const int head = gcol >> 6, dc = gcol & 63;
        const size_t bh = (size_t)bb * NHEAD + head;
        if (mat == 0)
          Qb[(bh * SEQ + ss) * DHEAD + dc] = (bf16)(v * 0.125f);  // pre-scale Q
        else if (mat == 1)
          Kb[(bh * SEQ + ss) * DHEAD + dc] = (bf16)v;
        else
          Vt[(bh * DHEAD + dc) * SEQ + ss] = (bf16)v;  // V transposed
      }
    }
  }
}

// ---------------------------------------------------------------------------
// Attention: one block per (b, head, 16-row q tile). 2 chunks of 512 cols with
// online softmax; scores fp32 in LDS (34 KB). QK^T and PV via 16x16x32 MFMA.
// ---------------------------------------------------------------------------
#define SCW 532  // padded row stride (floats): 16B-aligned, 2-way-max banks

__launch_bounds__(256, 2)
__global__ void attn_kernel(const bf16* __restrict__ Qb, const bf16* __restrict__ Kb,
                            const bf16* __restrict__ Vt, const float* __restrict__ bias,
                            const int* __restrict__ maskp, bf16* __restrict__ Ob) {
  __shared__ __align__(16) float Sc[16][SCW];
  __shared__ float mS[16], lS[16], aS[16];

  const int qt = blockIdx.x, hh = blockIdx.y, b = blockIdx.z;
  const int tid = threadIdx.x;
  const int lane = tid & 63, warp = tid >> 6;
  const int fr = lane & 15, quad = lane >> 4;

  const size_t bh = (size_t)b * NHEAD + hh;
  const bf16* Qp = Qb + (bh * SEQ + qt * 16) * DHEAD;
  const bf16* Kp = Kb + bh * SEQ * DHEAD;
  const bf16* Vp = Vt + (bh * DHEAD + warp * 16 + fr) * SEQ;

  // Q fragments (held all kernel): A[m=fr][k=quad*8+j], K split 0..31 / 32..63
  bf16x8 qa0 = *(const bf16x8*)(Qp + fr * DHEAD + quad * 8);
  bf16x8 qa1 = *(const bf16x8*)(Qp + fr * DHEAD + 32 + quad * 8);

  if (tid < 16) { mS[tid] = -1e30f; lS[tid] = 0.f; }
  floatx4 oacc = {0.f, 0.f, 0.f, 0.f};
  const int row = tid >> 4, jj = tid & 15;
  __syncthreads();

  for (int ch = 0; ch < 2; ++ch) {
    // ---- scores for columns [ch*512, ch*512+512) ----
#pragma unroll
    for (int t = 0; t < 8; ++t) {
      const int c0 = (t * 4 + warp) * 16;   // local col tile base
      const int gc = ch * 512 + c0 + fr;    // global col for this lane
      const bf16* kp = Kp + (size_t)gc * DHEAD;
      bf16x8 kb0 = *(const bf16x8*)(kp + quad * 8);
      bf16x8 kb1 = *(const bf16x8*)(kp + 32 + quad * 8);
      floatx4 st = {0.f, 0.f, 0.f, 0.f};
      st = mfma_bf16(qa0, kb0, st);
      st = mfma_bf16(qa1, kb1, st);
      const size_t qbase = (size_t)b * SEQ + qt * 16 + quad * 4;  // q row for r=0
      const float* bp = bias + (qbase * SEQ + gc) * NHEAD + hh;
      const int* mp = maskp + qbase * SEQ + gc;
#pragma unroll
      for (int r = 0; r < 4; ++r) {
        float v = st[r] + bp[(size_t)r * SEQ * NHEAD];
        const int mk = mp[(size_t)r * SEQ];
        Sc[quad * 4 + r][c0 + fr] = mk ? 0.0f : v;  // masked -> 1e-14 ~= 0
      }
    }
    __syncthreads();

    // ---- online softmax over this chunk (16 threads per row) ----
    {
      const float m_old = mS[row];
      float mx = m_old;
      for (int c = jj; c < 512; c += 16) mx = fmaxf(mx, Sc[row][c]);
#pragma unroll
      for (int o = 8; o >= 1; o >>= 1) mx = fmaxf(mx, __shfl_xor(mx, o, 64));
      float sum = 0.f;
      for (int c = jj; c < 512; c += 16) {
        float e = __expf(Sc[row][c] - mx);
        Sc[row][c] = e;
        sum += e;
      }
#pragma unroll
      for (int o = 8; o >= 1; o >>= 1) sum += __shfl_xor(sum, o, 64);
      if (jj == 0) {
        const float alpha = __expf(m_old - mx);
        aS[row] = alpha;
        lS[row] = lS[row] * alpha + sum;
        mS[row] = mx;
      }
    }
    __syncthreads();

    // ---- PV accumulate: O += P(chunk) @ V(chunk); wave w covers dv=w*16..+16
#pragma unroll
    for (int r = 0; r < 4; ++r) oacc[r] *= aS[quad * 4 + r];
    for (int k0 = 0; k0 < 512; k0 += 32) {
      const float* pr = &Sc[fr][k0 + quad * 8];
      float4 p0 = *(const float4*)(pr);
      float4 p1 = *(const float4*)(pr + 4);
      bf16x8 a;
      a[0] = (bf16)p0.x; a[1] = (bf16)p0.y; a[2] = (bf16)p0.z; a[3] = (bf16)p0.w;
      a[4] = (bf16)p1.x; a[5] = (bf16)p1.y; a[6] = (bf16)p1.z; a[7] = (bf16)p1.w;
      bf16x8 bv = *(const bf16x8*)(Vp + ch * 512 + k0 + quad * 8);
      oacc = mfma_bf16(a, bv, oacc);
    }
    __syncthreads();
  }

  // epilogue: normalize by 1/l and store Ob[b][s][hh*64+dv] (bf16)
  const size_t obase = ((size_t)b * SEQ + qt * 16) * HID + hh * DHEAD + warp * 16 + fr;
#pragma unroll
  for (int r = 0; r < 4; ++r) {
    const int q = quad * 4 + r;
    const float inv = 1.0f / lS[q];
    Ob[obase + (size_t)q * HID] = (bf16)(oacc[r] * inv);
  }
}

// ---------------------------------------------------------------------------
// Output projection: out = Ob @ Wo + bo (fp32 out), same tiling as qkv_gemm.
// ---------------------------------------------------------------------------
__launch_bounds__(256)
__global__ void out_gemm(const bf16* __restrict__ A, const bf16* __restrict__ W,
                         const float* __restrict__ bo, float* __restrict__ out) {
  __shared__ __align__(16) bf16 As[64][32];
  __shared__ __align__(16) bf16 Bs[64][32];
  const int bn = blockIdx.x * 64;
  const int bm = blockIdx.y * 64;
  const int tid = threadIdx.x;
  const int lane = tid & 63, warp = tid >> 6;
  const int fr = lane & 15, quad = lane >> 4;
  const int wm = (warp >> 1) * 32, wn = (warp & 1) * 32;

  floatx4 acc00 = {0.f, 0.f, 0.f, 0.f}, acc01 = {0.f, 0.f, 0.f, 0.f};
  floatx4 acc10 = {0.f, 0.f, 0.f, 0.f}, acc11 = {0.f, 0.f, 0.f, 0.f};

  const int sr = tid >> 2, scol = (tid & 3) * 8;
  const bf16* asrc = A + (size_t)(bm + sr) * HID + scol;
  const bf16* wsrc = W + (size_t)(bn + sr) * HID + scol;

  for (int k0 = 0; k0 < HID; k0 += 32) {
    uint4 a16 = *(const uint4*)(asrc + k0);
    uint4 w16 = *(const uint4*)(wsrc + k0);
    *(uint4*)&As[sr][scol] = a16;
    *(uint4*)&Bs[sr][scol] = w16;
    __syncthreads();
    bf16x8 a0 = *(const bf16x8*)&As[wm + fr][quad * 8];
    bf16x8 a1 = *(const bf16x8*)&As[wm + 16 + fr][quad * 8];
    bf16x8 b0 = *(const bf16x8*)&Bs[wn + fr][quad * 8];
    bf16x8 b1 = *(const bf16x8*)&Bs[wn + 16 + fr][quad * 8];
    acc00 = mfma_bf16(a0, b0, acc00);
    acc01 = mfma_bf16(a0, b1, acc01);
    acc10 = mfma_bf16(a1, b0, acc10);
    acc11 = mfma_bf16(a1, b1, acc11);
    __syncthreads();
  }

#pragma unroll
  for (int mi = 0; mi < 2; ++mi) {
#pragma unroll
    for (int ni = 0; ni < 2; ++ni) {
      floatx4 acc = (mi == 0) ? ((ni == 0) ? acc00 : acc01)
                              : ((ni == 0) ? acc10 : acc11);
#pragma unroll
      for (int r = 0; r < 4; ++r) {
        const int grow = bm + wm + mi * 16 + quad * 4 + r;
        const int gcol = bn + wn + ni * 16 + fr;
        out[(size_t)grow * HID + gcol] = acc[r] + bo[gcol];
      }
    }
  }
}

// ---------------------------------------------------------------------------
extern "C" void kernel_launch(void* const* d_in, const int* in_sizes, int n_in,
                              void* d_out, int out_size, void* d_ws, size_t ws_size,
                              hipStream_t stream) {
  const float* h  = (const float*)d_in[0];
  const float* ab = (const float*)d_in[1];
  const int*   mk = (const int*)d_in[2];
  const float* Wq = (const float*)d_in[3];
  const float* bq = (const float*)d_in[4];
  const float* Wk = (const float*)d_in[5];
  const float* bk = (const float*)d_in[6];
  const float* Wv = (const float*)d_in[7];
  const float* bv = (const float*)d_in[8];
  const float* Wo = (const float*)d_in[9];
  const float* bo = (const float*)d_in[10];
  float* out = (float*)d_out;

  // workspace layout (bf16): WT[4*768*768] | Qb | Kb | Vt | Ob  (~55 MB total)
  bf16* WT = (bf16*)d_ws;
  bf16* Qb = WT + (size_t)4 * WELEM;
  bf16* Kb = Qb + (size_t)QKVELEM;
  bf16* Vt = Kb + (size_t)QKVELEM;
  bf16* Ob = Vt + (size_t)QKVELEM;

  prep_weights<<<dim3(24, 24, 4), dim3(32, 8), 0, stream>>>(Wq, Wk, Wv, Wo, WT);
  qkv_gemm<<<dim3(12, 128, 3), 256, 0, stream>>>(h, WT, bq, bk, bv, Qb, Kb, Vt);
  attn_kernel<<<dim3(64, 12, 8), 256, 0, stream>>>(Qb, Kb, Vt, ab, mk, Ob);
  out_gemm<<<dim3(12, 128), 256, 0, stream>>>(Ob, WT + (size_t)3 * WELEM, bo, out);
}

// Round 2
// 883.211 us; speedup vs baseline: 1.2305x; 1.2305x over previous
//
#include <hip/hip_runtime.h>

// ---------------------------------------------------------------------------
// Attention_89361089560777: B=8, S=1024, H=768, nh=12, d=64
// Pipeline: prep_weights, prep_h -> qkv_gemm(128x128,m97) -> vtrans ->
//           attn (all-heads-per-block, coalesced bias staging) -> out_gemm
// ---------------------------------------------------------------------------

typedef __attribute__((ext_vector_type(8))) __bf16 bf16x8;
typedef __attribute__((ext_vector_type(4))) float floatx4;
using bf16 = __bf16;

#define HID 768
#define NHEAD 12
#define DHEAD 64
#define SEQ 1024
#define NBATCH 8
#define WELEM (HID * HID)                      // 589824
#define QKVELEM (NBATCH * NHEAD * SEQ * DHEAD) // 6291456

__device__ __forceinline__ floatx4 mfma_bf16(bf16x8 a, bf16x8 b, floatx4 c) {
  return __builtin_amdgcn_mfma_f32_16x16x32_bf16(a, b, c, 0, 0, 0);
}

// async global->LDS, 16B per lane; LDS dest must be wave-uniform base + lane*16
#define ASYNC16(gp, lp)                                           \
  __builtin_amdgcn_global_load_lds(                               \
      (__attribute__((address_space(1))) void*)(gp),              \
      (__attribute__((address_space(3))) void*)(lp), 16, 0, 0)

// ---------------------------------------------------------------------------
// Weight prep: WT[m][n][k] = bf16(W_m[k][n])
// ---------------------------------------------------------------------------
__global__ void prep_weights(const float* __restrict__ Wq, const float* __restrict__ Wk,
                             const float* __restrict__ Wv, const float* __restrict__ Wo,
                             bf16* __restrict__ WT) {
  __shared__ float t[32][33];
  const int m = blockIdx.z;
  const float* W = (m == 0) ? Wq : (m == 1) ? Wk : (m == 2) ? Wv : Wo;
  const int k0 = blockIdx.x * 32, n0 = blockIdx.y * 32;
  const int tx = threadIdx.x, ty = threadIdx.y;
#pragma unroll
  for (int i = 0; i < 4; ++i)
    t[ty + 8 * i][tx] = W[(size_t)(k0 + ty + 8 * i) * HID + n0 + tx];
  __syncthreads();
  bf16* o = WT + (size_t)m * WELEM;
#pragma unroll
  for (int i = 0; i < 4; ++i)
    o[(size_t)(n0 + ty + 8 * i) * HID + k0 + tx] = (bf16)t[tx][ty + 8 * i];
}

// h (fp32) -> hb (bf16), 8 elems/thread
__global__ void prep_h(const float* __restrict__ X, bf16* __restrict__ Y) {
  const size_t i = ((size_t)blockIdx.x * 256 + threadIdx.x) * 8;
  float4 a = *(const float4*)(X + i);
  float4 b = *(const float4*)(X + i + 4);
  bf16x8 o;
  o[0] = (bf16)a.x; o[1] = (bf16)a.y; o[2] = (bf16)a.z; o[3] = (bf16)a.w;
  o[4] = (bf16)b.x; o[5] = (bf16)b.y; o[6] = (bf16)b.z; o[7] = (bf16)b.w;
  *(bf16x8*)(Y + i) = o;
}

// ---------------------------------------------------------------------------
// QKV GEMM, m97 structure: 128x128 tile, BK=32, global_load_lds w16.
// A = hb [8192][768] bf16, B = WT[mat] [n][k] bf16.
// mat0 -> Qb [b,h,s,d]*0.125 ; mat1 -> Kb [b,h,s,d] ; mat2 -> Vb [b,h,s,d]
// ---------------------------------------------------------------------------
__launch_bounds__(256, 2)
__global__ void qkv_gemm(const bf16* __restrict__ A, const bf16* __restrict__ WT,
                         const float* __restrict__ bq, const float* __restrict__ bk,
                         const float* __restrict__ bv,
                         bf16* __restrict__ Qb, bf16* __restrict__ Kb,
                         bf16* __restrict__ Vb) {
  __shared__ __align__(16) bf16 As[128][32];
  __shared__ __align__(16) bf16 Bs[128][32];
  const int mat = blockIdx.z;
  const int bn = blockIdx.x * 128, bm = blockIdx.y * 128;
  const bf16* W = WT + (size_t)mat * WELEM;
  const int tid = threadIdx.x, lane = tid & 63, warp = tid >> 6;
  const int fr = lane & 15, quad = lane >> 4;
  const int wr = warp >> 1, wc = warp & 1;

  floatx4 acc[4][4] = {};

  const int srow = tid >> 2, scol = (tid & 3) * 8;
  const bf16* as0 = A + (size_t)(bm + srow) * HID + scol;
  const bf16* as1 = A + (size_t)(bm + 64 + srow) * HID + scol;
  const bf16* bs0 = W + (size_t)(bn + srow) * HID + scol;
  const bf16* bs1 = W + (size_t)(bn + 64 + srow) * HID + scol;
  bf16* la0 = &As[srow][scol];
  bf16* la1 = &As[64 + srow][scol];
  bf16* lb0 = &Bs[srow][scol];
  bf16* lb1 = &Bs[64 + srow][scol];

  for (int k0 = 0; k0 < HID; k0 += 32) {
    ASYNC16(as0 + k0, la0);
    ASYNC16(as1 + k0, la1);
    ASYNC16(bs0 + k0, lb0);
    ASYNC16(bs1 + k0, lb1);
    __syncthreads();
    bf16x8 a[4], b[4];
#pragma unroll
    for (int mi = 0; mi < 4; ++mi) a[mi] = *(const bf16x8*)&As[wr * 64 + mi * 16 + fr][quad * 8];
#pragma unroll
    for (int ni = 0; ni < 4; ++ni) b[ni] = *(const bf16x8*)&Bs[wc * 64 + ni * 16 + fr][quad * 8];
#pragma unroll
    for (int mi = 0; mi < 4; ++mi)
#pragma unroll
      for (int ni = 0; ni < 4; ++ni) acc[mi][ni] = mfma_bf16(a[mi], b[ni], acc[mi][ni]);
    __syncthreads();
  }

  const float* bias = (mat == 0) ? bq : (mat == 1) ? bk : bv;
#pragma unroll
  for (int mi = 0; mi < 4; ++mi)
#pragma unroll
    for (int ni = 0; ni < 4; ++ni)
#pragma unroll
      for (int r = 0; r < 4; ++r) {
        const int grow = bm + wr * 64 + mi * 16 + quad * 4 + r;
        const int gcol = bn + wc * 64 + ni * 16 + fr;
        float v = acc[mi][ni][r] + bias[gcol];
        const int bb = grow >> 10, ss = grow & 1023;
        const int head = gcol >> 6, dc = gcol & 63;
        const size_t bh = (size_t)bb * NHEAD + head;
        const size_t idx = (bh * SEQ + ss) * DHEAD + dc;
        if (mat == 0) Qb[idx] = (bf16)(v * 0.125f);
        else if (mat == 1) Kb[idx] = (bf16)v;
        else Vb[idx] = (bf16)v;
      }
}

// ---------------------------------------------------------------------------
// V transpose: Vb [bh][s][d] -> Vt [bh][d][s], 64x64 LDS tiles
// ---------------------------------------------------------------------------
__global__ void vtrans(const bf16* __restrict__ Vb, bf16* __restrict__ Vt) {
  __shared__ bf16 t[64][72];
  const int st = blockIdx.x, bh = blockIdx.y;
  const int tid = threadIdx.x;
  const bf16* src = Vb + ((size_t)bh * SEQ + st * 64) * DHEAD;
#pragma unroll
  for (int p = 0; p < 2; ++p) {
    const int r = p * 32 + (tid >> 3), c = (tid & 7) * 8;
    *(bf16x8*)&t[r][c] = *(const bf16x8*)(src + (size_t)r * DHEAD + c);
  }
  __syncthreads();
#pragma unroll
  for (int p = 0; p < 2; ++p) {
    const int d = p * 32 + (tid >> 3), s0 = (tid & 7) * 8;
    bf16x8 o;
#pragma unroll
    for (int k = 0; k < 8; ++k) o[k] = t[s0 + k][d];
    *(bf16x8*)(Vt + ((size_t)bh * DHEAD + d) * SEQ + st * 64 + s0) = o;
  }
}

// ---------------------------------------------------------------------------
// Attention: block = (qt, b), 16 q-rows, ALL 12 heads (3 per wave).
// k-chunks of 32 with online softmax; bias slab [16][32][12] staged to LDS
// via register prefetch (coalesced, one chunk ahead); mask prefetched to regs.
// P never leaves registers between softmax and PV.
// ---------------------------------------------------------------------------
__launch_bounds__(256, 2)
__global__ void attn_kernel(const bf16* __restrict__ Qb, const bf16* __restrict__ Kb,
                            const bf16* __restrict__ Vt, const float* __restrict__ bias,
                            const int* __restrict__ maskp, bf16* __restrict__ Ob) {
  __shared__ __align__(16) float Bb[16 * 32 * 12];  // bias stage [q][c][h], 24 KB
  __shared__ __align__(16) float Sc[NHEAD][16][36]; // scores, padded, 27.6 KB

  const int qt = blockIdx.x, b = blockIdx.y;
  const int tid = threadIdx.x, lane = tid & 63, warp = tid >> 6;
  const int fr = lane & 15, quad = lane >> 4;
  const size_t brow = (size_t)b * SEQ + qt * 16;  // global q-row base

  // Q fragments for this wave's 3 heads (pre-scaled by 1/8 in qkv_gemm)
  bf16x8 qa0[3], qa1[3];
#pragma unroll
  for (int j = 0; j < 3; ++j) {
    const size_t bh = (size_t)b * NHEAD + 3 * warp + j;
    const bf16* Qp = Qb + (bh * SEQ + qt * 16) * DHEAD;
    qa0[j] = *(const bf16x8*)(Qp + fr * DHEAD + quad * 8);
    qa1[j] = *(const bf16x8*)(Qp + fr * DHEAD + 32 + quad * 8);
  }

  float mrun[3] = {-1e30f, -1e30f, -1e30f};
  float lrun[3] = {0.f, 0.f, 0.f};
  floatx4 oacc[3][4] = {};

  // ---- chunk 0 staging ----
  float4 breg[6];
  int mreg[8];
  {
#pragma unroll
    for (int i = 0; i < 6; ++i) {
      const int f = tid + 256 * i, q = f / 96, rem = f % 96;
      breg[i] = *((const float4*)bias + ((brow + q) * SEQ + 0) * 3 + rem);
    }
#pragma unroll
    for (int ct = 0; ct < 2; ++ct)
#pragma unroll
      for (int r = 0; r < 4; ++r)
        mreg[ct * 4 + r] = maskp[(brow + quad * 4 + r) * SEQ + ct * 16 + fr];
#pragma unroll
    for (int i = 0; i < 6; ++i) ((float4*)Bb)[tid + 256 * i] = breg[i];
  }
  __syncthreads();

  for (int ch = 0; ch < 32; ++ch) {
    const int c0 = ch * 32;
    // ---- prefetch chunk ch+1 into registers ----
    float4 bnext[6];
    int mnext[8];
    if (ch < 31) {
      const int cn = c0 + 32;
#pragma unroll
      for (int i = 0; i < 6; ++i) {
        const int f = tid + 256 * i, q = f / 96, rem = f % 96;
        bnext[i] = *((const float4*)bias + ((brow + q) * SEQ + cn) * 3 + rem);
      }
#pragma unroll
      for (int ct = 0; ct < 2; ++ct)
#pragma unroll
        for (int r = 0; r < 4; ++r)
          mnext[ct * 4 + r] = maskp[(brow + quad * 4 + r) * SEQ + cn + ct * 16 + fr];
    }

    // ---- scores: QK^T + bias, mask -> Sc (C-layout scatter) ----
#pragma unroll
    for (int ct = 0; ct < 2; ++ct) {
#pragma unroll
      for (int j = 0; j < 3; ++j) {
        const int hh = 3 * warp + j;
        const size_t bh = (size_t)b * NHEAD + hh;
        const bf16* kp = Kb + (bh * SEQ + c0 + ct * 16 + fr) * DHEAD;
        bf16x8 kb0 = *(const bf16x8*)(kp + quad * 8);
        bf16x8 kb1 = *(const bf16x8*)(kp + 32 + quad * 8);
        floatx4 st = {0.f, 0.f, 0.f, 0.f};
        st = mfma_bf16(qa0[j], kb0, st);
        st = mfma_bf16(qa1[j], kb1, st);
#pragma unroll
        for (int r = 0; r < 4; ++r) {
          const float bvl = Bb[((quad * 4 + r) * 32 + ct * 16 + fr) * 12 + hh];
          Sc[hh][quad * 4 + r][ct * 16 + fr] = mreg[ct * 4 + r] ? 0.0f : (st[r] + bvl);
        }
      }
    }

    // ---- per-head online softmax (row = fr, cols quad*8..) + PV ----
#pragma unroll
    for (int j = 0; j < 3; ++j) {
      const int hh = 3 * warp + j;
      float4 sa = *(const float4*)&Sc[hh][fr][quad * 8];
      float4 sb = *(const float4*)&Sc[hh][fr][quad * 8 + 4];
      float s[8] = {sa.x, sa.y, sa.z, sa.w, sb.x, sb.y, sb.z, sb.w};
      float mx = mrun[j];
#pragma unroll
      for (int k = 0; k < 8; ++k) mx = fmaxf(mx, s[k]);
      mx = fmaxf(mx, __shfl_xor(mx, 16));
      mx = fmaxf(mx, __shfl_xor(mx, 32));
      const float alpha = __expf(mrun[j] - mx);
      float e[8], sum = 0.f;
#pragma unroll
      for (int k = 0; k < 8; ++k) { e[k] = __expf(s[k] - mx); sum += e[k]; }
      sum += __shfl_xor(sum, 16);
      sum += __shfl_xor(sum, 32);
      lrun[j] = lrun[j] * alpha + sum;
      mrun[j] = mx;
      bf16x8 pa;
#pragma unroll
      for (int k = 0; k < 8; ++k) pa[k] = (bf16)e[k];
      float ar[4];
#pragma unroll
      for (int r = 0; r < 4; ++r) ar[r] = __shfl(alpha, quad * 4 + r);
      const size_t bh = (size_t)b * NHEAD + hh;
#pragma unroll
      for (int dvt = 0; dvt < 4; ++dvt) {
#pragma unroll
        for (int r = 0; r < 4; ++r) oacc[j][dvt][r] *= ar[r];
        const bf16* vp = Vt + (bh * DHEAD + dvt * 16 + fr) * SEQ + c0 + quad * 8;
        bf16x8 vb = *(const bf16x8*)vp;
        oacc[j][dvt] = mfma_bf16(pa, vb, oacc[j][dvt]);
      }
    }

    __syncthreads();  // all waves done reading Bb for chunk ch
    if (ch < 31) {
#pragma unroll
      for (int i = 0; i < 6; ++i) ((float4*)Bb)[tid + 256 * i] = bnext[i];
#pragma unroll
      for (int i = 0; i < 8; ++i) mreg[i] = mnext[i];
    }
    __syncthreads();  // Bb ready for chunk ch+1
  }

  // ---- epilogue: O / l -> Ob [b][s][hh*64+dv] ----
#pragma unroll
  for (int j = 0; j < 3; ++j) {
    const int hh = 3 * warp + j;
    const float linv = 1.0f / lrun[j];
    float lr[4];
#pragma unroll
    for (int r = 0; r < 4; ++r) lr[r] = __shfl(linv, quad * 4 + r);
#pragma unroll
    for (int dvt = 0; dvt < 4; ++dvt)
#pragma unroll
      for (int r = 0; r < 4; ++r)
        Ob[(brow + quad * 4 + r) * HID + hh * 64 + dvt * 16 + fr] =
            (bf16)(oacc[j][dvt][r] * lr[r]);
  }
}

// ---------------------------------------------------------------------------
// Output projection, m97 structure: out = Ob @ Wo + bo (fp32)
// ---------------------------------------------------------------------------
__launch_bounds__(256, 2)
__global__ void out_gemm(const bf16* __restrict__ A, const bf16* __restrict__ W,
                         const float* __restrict__ bo, float* __restrict__ out) {
  __shared__ __align__(16) bf16 As[128][32];
  __shared__ __align__(16) bf16 Bs[128][32];
  const int bn = blockIdx.x * 128, bm = blockIdx.y * 128;
  const int tid = threadIdx.x, lane = tid & 63, warp = tid >> 6;
  const int fr = lane & 15, quad = lane >> 4;
  const int wr = warp >> 1, wc = warp & 1;

  floatx4 acc[4][4] = {};

  const int srow = tid >> 2, scol = (tid & 3) * 8;
  const bf16* as0 = A + (size_t)(bm + srow) * HID + scol;
  const bf16* as1 = A + (size_t)(bm + 64 + srow) * HID + scol;
  const bf16* bs0 = W + (size_t)(bn + srow) * HID + scol;
  const bf16* bs1 = W + (size_t)(bn + 64 + srow) * HID + scol;
  bf16* la0 = &As[srow][scol];
  bf16* la1 = &As[64 + srow][scol];
  bf16* lb0 = &Bs[srow][scol];
  bf16* lb1 = &Bs[64 + srow][scol];

  for (int k0 = 0; k0 < HID; k0 += 32) {
    ASYNC16(as0 + k0, la0);
    ASYNC16(as1 + k0, la1);
    ASYNC16(bs0 + k0, lb0);
    ASYNC16(bs1 + k0, lb1);
    __syncthreads();
    bf16x8 a[4], b[4];
#pragma unroll
    for (int mi = 0; mi < 4; ++mi) a[mi] = *(const bf16x8*)&As[wr * 64 + mi * 16 + fr][quad * 8];
#pragma unroll
    for (int ni = 0; ni < 4; ++ni) b[ni] = *(const bf16x8*)&Bs[wc * 64 + ni * 16 + fr][quad * 8];
#pragma unroll
    for (int mi = 0; mi < 4; ++mi)
#pragma unroll
      for (int ni = 0; ni < 4; ++ni) acc[mi][ni] = mfma_bf16(a[mi], b[ni], acc[mi][ni]);
    __syncthreads();
  }

#pragma unroll
  for (int mi = 0; mi < 4; ++mi)
#pragma unroll
    for (int ni = 0; ni < 4; ++ni)
#pragma unroll
      for (int r = 0; r < 4; ++r) {
        const int grow = bm + wr * 64 + mi * 16 + quad * 4 + r;
        const int gcol = bn + wc * 64 + ni * 16 + fr;
        out[(size_t)grow * HID + gcol] = acc[mi][ni][r] + bo[gcol];
      }
}

// ---------------------------------------------------------------------------
extern "C" void kernel_launch(void* const* d_in, const int* in_sizes, int n_in,
                              void* d_out, int out_size, void* d_ws, size_t ws_size,
                              hipStream_t stream) {
  const float* h  = (const float*)d_in[0];
  const float* ab = (const float*)d_in[1];
  const int*   mk = (const int*)d_in[2];
  const float* Wq = (const float*)d_in[3];
  const float* bq = (const float*)d_in[4];
  const float* Wk = (const float*)d_in[5];
  const float* bk = (const float*)d_in[6];
  const float* Wv = (const float*)d_in[7];
  const float* bv = (const float*)d_in[8];
  const float* Wo = (const float*)d_in[9];
  const float* bo = (const float*)d_in[10];
  float* out = (float*)d_out;

  // ws (bf16): WT[4*W] | hb | Qb | Kb | Vb | Vt ; Ob reuses Vb (dead after vtrans)
  bf16* WT = (bf16*)d_ws;
  bf16* hb = WT + (size_t)4 * WELEM;
  bf16* Qb = hb + (size_t)QKVELEM;
  bf16* Kb = Qb + (size_t)QKVELEM;
  bf16* Vb = Kb + (size_t)QKVELEM;
  bf16* Vt = Vb + (size_t)QKVELEM;
  bf16* Ob = Vb;  // reuse

  prep_weights<<<dim3(24, 24, 4), dim3(32, 8), 0, stream>>>(Wq, Wk, Wv, Wo, WT);
  prep_h<<<3072, 256, 0, stream>>>(h, hb);
  qkv_gemm<<<dim3(6, 64, 3), 256, 0, stream>>>(hb, WT, bq, bk, bv, Qb, Kb, Vb);
  vtrans<<<dim3(16, 96), 256, 0, stream>>>(Vb, Vt);
  attn_kernel<<<dim3(64, 8), 256, 0, stream>>>(Qb, Kb, Vt, ab, mk, Ob);
  out_gemm<<<dim3(6, 64), 256, 0, stream>>>(Ob, WT + (size_t)3 * WELEM, bo, out);
}